// Round 1
// baseline (1907.139 us; speedup 1.0000x reference)
//
#include <hip/hip_runtime.h>

#define L 2048
#define D 1024
#define H 16
#define Z 64
#define HZ 1024

// ---------------------------------------------------------------------------
// proj: kp/qp[b,h,l,z] = sum_d x[b,l,d] * W[h,z,d]     (NT GEMM, K fast both)
// grid (16 n-tiles, 64 m-tiles, 2 {Wk,Wq}), 256 thr, 64x64 tile, 4x4/thread
// ---------------------------------------------------------------------------
__global__ __launch_bounds__(256) void proj_kernel(
    const float* __restrict__ x, const float* __restrict__ Wk,
    const float* __restrict__ Wq, float* __restrict__ kp, float* __restrict__ qp)
{
  const float* __restrict__ W = blockIdx.z ? Wq : Wk;
  float* __restrict__ out = blockIdx.z ? qp : kp;
  const int n0 = blockIdx.x * 64;
  const int m0 = blockIdx.y * 64;
  const int t = threadIdx.x, tx = t & 15, ty = t >> 4;
  __shared__ float As[64][20];   // [m][k] pitch 20 -> 80B rows, b128-aligned
  __shared__ float Bt[64][20];   // [n][k]
  const int sm = t >> 2;         // staging row 0..63
  const int sk = (t & 3) << 2;   // staging col 0,4,8,12
  float acc[4][4] = {};
  for (int k0 = 0; k0 < D; k0 += 16) {
    float4 av = *(const float4*)(x + (size_t)(m0 + sm) * D + k0 + sk);
    float4 bv = *(const float4*)(W + (size_t)(n0 + sm) * D + k0 + sk);
    __syncthreads();
    *(float4*)&As[sm][sk] = av;
    *(float4*)&Bt[sm][sk] = bv;
    __syncthreads();
#pragma unroll
    for (int kc = 0; kc < 16; kc += 4) {
      float4 a[4], b[4];
#pragma unroll
      for (int i = 0; i < 4; i++) a[i] = *(const float4*)&As[ty + 16*i][kc];
#pragma unroll
      for (int j = 0; j < 4; j++) b[j] = *(const float4*)&Bt[tx + 16*j][kc];
#pragma unroll
      for (int i = 0; i < 4; i++)
#pragma unroll
        for (int j = 0; j < 4; j++) {
          acc[i][j] += a[i].x * b[j].x; acc[i][j] += a[i].y * b[j].y;
          acc[i][j] += a[i].z * b[j].z; acc[i][j] += a[i].w * b[j].w;
        }
    }
  }
#pragma unroll
  for (int i = 0; i < 4; i++) {
    int m = m0 + ty + 16*i;            // m = b*L + l
    int b = m >> 11, l = m & (L - 1);
#pragma unroll
    for (int j = 0; j < 4; j++) {
      int n = n0 + tx + 16*j;          // n = h*Z + z
      int h = n >> 6, z = n & 63;
      out[(((size_t)(b * H + h) * L) + l) * Z + z] = acc[i][j];
    }
  }
}

// ---------------------------------------------------------------------------
// lse[b,h,q] = logsumexp_k( beta * <kp[q], qp[k]> )  (online, streaming k-tiles)
// grid (32 q-tiles, 32 bh), 256 thr. Rows r_i = ty+16i, cols c_j = tx+16j.
// ---------------------------------------------------------------------------
__global__ __launch_bounds__(256) void lse_kernel(
    const float* __restrict__ kp, const float* __restrict__ qp,
    const float* __restrict__ beta_p, float* __restrict__ lse_ws)
{
  const int qt = blockIdx.x, bh = blockIdx.y;
  const float beta = beta_p[0];
  const int t = threadIdx.x, tx = t & 15, ty = t >> 4;
  __shared__ float R[64][68];    // resident kp tile [q][z]
  __shared__ float Sm[64][68];   // streamed qp tile [k][z]
  const float* kpb = kp + (size_t)bh * L * Z;
  const float* qpb = qp + (size_t)bh * L * Z;
#pragma unroll
  for (int it = 0; it < 4; it++) {
    int row = ty + 16*it, z = tx << 2;
    *(float4*)&R[row][z] = *(const float4*)(kpb + (size_t)(qt*64 + row) * Z + z);
  }
  float mi[4], si[4];
#pragma unroll
  for (int i = 0; i < 4; i++) { mi[i] = -1e30f; si[i] = 0.f; }
  for (int kt = 0; kt < 32; kt++) {
    __syncthreads();
#pragma unroll
    for (int it = 0; it < 4; it++) {
      int row = ty + 16*it, z = tx << 2;
      *(float4*)&Sm[row][z] = *(const float4*)(qpb + (size_t)(kt*64 + row) * Z + z);
    }
    __syncthreads();
    float st[4][4] = {};
#pragma unroll
    for (int zc = 0; zc < 64; zc += 4) {
      float4 a[4], b[4];
#pragma unroll
      for (int i = 0; i < 4; i++) a[i] = *(const float4*)&R[ty + 16*i][zc];
#pragma unroll
      for (int j = 0; j < 4; j++) b[j] = *(const float4*)&Sm[tx + 16*j][zc];
#pragma unroll
      for (int i = 0; i < 4; i++)
#pragma unroll
        for (int j = 0; j < 4; j++) {
          st[i][j] += a[i].x * b[j].x; st[i][j] += a[i].y * b[j].y;
          st[i][j] += a[i].z * b[j].z; st[i][j] += a[i].w * b[j].w;
        }
    }
    // online softmax stats per row; 16 lanes (same ty) share each row group
#pragma unroll
    for (int i = 0; i < 4; i++) {
      float s0 = st[i][0] * beta, s1 = st[i][1] * beta;
      float s2 = st[i][2] * beta, s3 = st[i][3] * beta;
      float rmax = fmaxf(fmaxf(s0, s1), fmaxf(s2, s3));
#pragma unroll
      for (int off = 1; off < 16; off <<= 1)
        rmax = fmaxf(rmax, __shfl_xor(rmax, off, 64));
      float nm = fmaxf(mi[i], rmax);
      float ps = __expf(s0 - nm) + __expf(s1 - nm) + __expf(s2 - nm) + __expf(s3 - nm);
#pragma unroll
      for (int off = 1; off < 16; off <<= 1)
        ps += __shfl_xor(ps, off, 64);
      si[i] = si[i] * __expf(mi[i] - nm) + ps;
      mi[i] = nm;
    }
  }
  if (tx == 0) {
#pragma unroll
    for (int i = 0; i < 4; i++)
      lse_ws[(size_t)bh * L + qt*64 + ty + 16*i] = mi[i] + __logf(si[i]);
  }
}

// ---------------------------------------------------------------------------
// MODE 0: Gkp[q,z] = sum_k exp(b*S[q,k]-lse[q]) * qp[k,z]   (stored negated)
// MODE 1: Gqp[k,z] = sum_q exp(b*S[q,k]-lse[q]) * kp[q,z]   (roles swapped,
//         lse indexed by the streamed column)
// grid (32 resident tiles, 32 bh), 256 thr.
// ---------------------------------------------------------------------------
template<int MODE>
__global__ __launch_bounds__(256) void grad_kernel(
    const float* __restrict__ kp, const float* __restrict__ qp,
    const float* __restrict__ lse_ws, const float* __restrict__ beta_p,
    float* __restrict__ Gout)
{
  const int rt = blockIdx.x, bh = blockIdx.y;
  const float beta = beta_p[0];
  const int t = threadIdx.x, tx = t & 15, ty = t >> 4;
  __shared__ float R[64][68];    // resident tile [r][z]
  __shared__ float Sm[64][68];   // streamed tile [s][z]
  __shared__ float Pt[64][68];   // P tile [r][s]
  const float* __restrict__ Rg = (MODE == 0 ? kp : qp) + (size_t)bh * L * Z;
  const float* __restrict__ Sg = (MODE == 0 ? qp : kp) + (size_t)bh * L * Z;
  const float* __restrict__ lseb = lse_ws + (size_t)bh * L;
#pragma unroll
  for (int it = 0; it < 4; it++) {
    int row = ty + 16*it, z = tx << 2;
    *(float4*)&R[row][z] = *(const float4*)(Rg + (size_t)(rt*64 + row) * Z + z);
  }
  float lse_r[4] = {0.f, 0.f, 0.f, 0.f};
  if (MODE == 0) {
#pragma unroll
    for (int i = 0; i < 4; i++) lse_r[i] = lseb[rt*64 + ty + 16*i];
  }
  float acc[4][4] = {};
  for (int stt = 0; stt < 32; stt++) {
    __syncthreads();
#pragma unroll
    for (int it = 0; it < 4; it++) {
      int row = ty + 16*it, z = tx << 2;
      *(float4*)&Sm[row][z] = *(const float4*)(Sg + (size_t)(stt*64 + row) * Z + z);
    }
    float lse_c[4] = {0.f, 0.f, 0.f, 0.f};
    if (MODE == 1) {
#pragma unroll
      for (int j = 0; j < 4; j++) lse_c[j] = lseb[stt*64 + tx + 16*j];
    }
    __syncthreads();
    // S phase: S[r][c] = sum_z R[r][z]*Sm[c][z]
    float st[4][4] = {};
#pragma unroll
    for (int zc = 0; zc < 64; zc += 4) {
      float4 a[4], b[4];
#pragma unroll
      for (int i = 0; i < 4; i++) a[i] = *(const float4*)&R[ty + 16*i][zc];
#pragma unroll
      for (int j = 0; j < 4; j++) b[j] = *(const float4*)&Sm[tx + 16*j][zc];
#pragma unroll
      for (int i = 0; i < 4; i++)
#pragma unroll
        for (int j = 0; j < 4; j++) {
          st[i][j] += a[i].x * b[j].x; st[i][j] += a[i].y * b[j].y;
          st[i][j] += a[i].z * b[j].z; st[i][j] += a[i].w * b[j].w;
        }
    }
    // P = exp(beta*S - lse)
#pragma unroll
    for (int i = 0; i < 4; i++)
#pragma unroll
      for (int j = 0; j < 4; j++) {
        float sub = (MODE == 0) ? lse_r[i] : lse_c[j];
        Pt[ty + 16*i][tx + 16*j] = __expf(beta * st[i][j] - sub);
      }
    __syncthreads();
    // PV phase: acc[r][z] += sum_s Pt[r][s]*Sm[s][z]
#pragma unroll
    for (int sc = 0; sc < 64; sc += 4) {
      float pr[4][4];
#pragma unroll
      for (int i = 0; i < 4; i++) {
        float4 v = *(const float4*)&Pt[ty + 16*i][sc];
        pr[i][0] = v.x; pr[i][1] = v.y; pr[i][2] = v.z; pr[i][3] = v.w;
      }
#pragma unroll
      for (int kk = 0; kk < 4; kk++) {
        float bj[4];
#pragma unroll
        for (int j = 0; j < 4; j++) bj[j] = Sm[sc + kk][tx + 16*j];
#pragma unroll
        for (int i = 0; i < 4; i++)
#pragma unroll
          for (int j = 0; j < 4; j++) acc[i][j] += pr[i][kk] * bj[j];
      }
    }
  }
  const int b = bh >> 4, h = bh & 15;
#pragma unroll
  for (int i = 0; i < 4; i++) {
    int l = rt*64 + ty + 16*i;
#pragma unroll
    for (int j = 0; j < 4; j++) {
      int z = tx + 16*j;
      Gout[(size_t)(b * L + l) * HZ + h * Z + z] = -acc[i][j];
    }
  }
}

// ---------------------------------------------------------------------------
// en[b] = -(1/beta) * sum_{h,q} lse[b,h,q]
// ---------------------------------------------------------------------------
__global__ __launch_bounds__(256) void energy_kernel(
    const float* __restrict__ lse_ws, const float* __restrict__ beta_p,
    float* __restrict__ out)
{
  const int b = blockIdx.x;
  const float* p = lse_ws + (size_t)b * H * L;
  float sum = 0.f;
  for (int i = threadIdx.x; i < H * L; i += 256) sum += p[i];
#pragma unroll
  for (int off = 1; off < 64; off <<= 1) sum += __shfl_xor(sum, off, 64);
  __shared__ float wsum[4];
  if ((threadIdx.x & 63) == 0) wsum[threadIdx.x >> 6] = sum;
  __syncthreads();
  if (threadIdx.x == 0)
    out[b] = -(wsum[0] + wsum[1] + wsum[2] + wsum[3]) / beta_p[0];
}

// ---------------------------------------------------------------------------
// gx[m,d] = sum_j Gkp[m,j]*Wk[j,d] + Gqp[m,j]*Wq[j,d]   (NN GEMM, two passes)
// grid (16 d-tiles, 64 m-tiles), 256 thr.
// ---------------------------------------------------------------------------
__global__ __launch_bounds__(256) void gx_kernel(
    const float* __restrict__ Gkp, const float* __restrict__ Gqp,
    const float* __restrict__ Wk, const float* __restrict__ Wq,
    float* __restrict__ gx)
{
  const int n0 = blockIdx.x * 64;
  const int m0 = blockIdx.y * 64;
  const int t = threadIdx.x, tx = t & 15, ty = t >> 4;
  __shared__ float As[64][20];   // [m][k]
  __shared__ float Bs[16][68];   // [k][d]
  const int sm = t >> 2, sk = (t & 3) << 2;
  const int bk = t >> 4, bd = (t & 15) << 2;
  float acc[4][4] = {};
#pragma unroll 1
  for (int src = 0; src < 2; src++) {
    const float* __restrict__ A  = src ? Gqp : Gkp;
    const float* __restrict__ Bw = src ? Wq : Wk;
    for (int k0 = 0; k0 < HZ; k0 += 16) {
      float4 av = *(const float4*)(A + (size_t)(m0 + sm) * HZ + k0 + sk);
      float4 bv = *(const float4*)(Bw + (size_t)(k0 + bk) * D + n0 + bd);
      __syncthreads();
      *(float4*)&As[sm][sk] = av;
      *(float4*)&Bs[bk][bd] = bv;
      __syncthreads();
#pragma unroll
      for (int kc = 0; kc < 16; kc += 4) {
        float ar[4][4];
#pragma unroll
        for (int i = 0; i < 4; i++) {
          float4 v = *(const float4*)&As[ty + 16*i][kc];
          ar[i][0] = v.x; ar[i][1] = v.y; ar[i][2] = v.z; ar[i][3] = v.w;
        }
#pragma unroll
        for (int kk = 0; kk < 4; kk++) {
          float bj[4];
#pragma unroll
          for (int j = 0; j < 4; j++) bj[j] = Bs[kc + kk][tx + 16*j];
#pragma unroll
          for (int i = 0; i < 4; i++)
#pragma unroll
            for (int j = 0; j < 4; j++) acc[i][j] += ar[i][kk] * bj[j];
        }
      }
    }
  }
#pragma unroll
  for (int i = 0; i < 4; i++)
#pragma unroll
    for (int j = 0; j < 4; j++)
      gx[(size_t)(m0 + ty + 16*i) * D + n0 + tx + 16*j] = acc[i][j];
}

// ---------------------------------------------------------------------------
extern "C" void kernel_launch(void* const* d_in, const int* in_sizes, int n_in,
                              void* d_out, int out_size, void* d_ws, size_t ws_size,
                              hipStream_t stream)
{
  const float* x    = (const float*)d_in[0];
  const float* Wq   = (const float*)d_in[1];
  const float* Wk   = (const float*)d_in[2];
  const float* beta = (const float*)d_in[3];
  float* out = (float*)d_out;

  // workspace layout (floats): kp 4M | qp 4M | Gkp 4M | Gqp 4M | lse 64K
  float* ws  = (float*)d_ws;
  float* kp  = ws;
  float* qp  = ws + 4194304;
  float* Gkp = ws + 8388608;
  float* Gqp = ws + 12582912;
  float* lse = ws + 16777216;

  proj_kernel<<<dim3(16, 64, 2), 256, 0, stream>>>(x, Wk, Wq, kp, qp);
  lse_kernel<<<dim3(32, 32), 256, 0, stream>>>(kp, qp, beta, lse);
  grad_kernel<0><<<dim3(32, 32), 256, 0, stream>>>(kp, qp, lse, beta, Gkp);
  grad_kernel<1><<<dim3(32, 32), 256, 0, stream>>>(kp, qp, lse, beta, Gqp);
  energy_kernel<<<dim3(2), 256, 0, stream>>>(lse, beta, out);
  gx_kernel<<<dim3(16, 64), 256, 0, stream>>>(Gkp, Gqp, Wk, Wq, out + 2);
}

// Round 2
// 437.918 us; speedup vs baseline: 4.3550x; 4.3550x over previous
//
#include <hip/hip_runtime.h>

#define L 2048
#define D 1024
#define H 16
#define Z 64
#define HZ 1024

typedef __bf16 bf16x8 __attribute__((ext_vector_type(8)));
typedef float f32x4 __attribute__((ext_vector_type(4)));

// ---------------------------------------------------------------------------
// Fragment-ordered 64x64 bf16 tile in LDS: 8 regions of 1 KB.
//   region = (row/16)*2 + (k/32)
//   lane l of a region holds rows (row/16)*16 + (l&15), k = (k/32)*32 + (l>>4)*8 + 0..7
// Fragment reads are then a linear lane*16B b128 -> conflict-free.
// ---------------------------------------------------------------------------
__device__ __forceinline__ void stage64(const __bf16* __restrict__ g, int gstride,
                                        char* lds, int tid) {
  const int lane = tid & 63, w = tid >> 6;
#pragma unroll
  for (int it = 0; it < 2; ++it) {
    const int region = it * 4 + w;
    const int r = ((region >> 1) << 4) + (lane & 15);
    const int c = ((region & 1) << 2) + (lane >> 4);
    const uint4 v = *(const uint4*)(g + (size_t)r * gstride + c * 8);
    *(uint4*)(lds + (region << 10) + (lane << 4)) = v;
  }
}

__device__ __forceinline__ bf16x8 frag(const char* lds, int blk, int t, int lane) {
  return *(const bf16x8*)(lds + (((blk << 1) + t) << 10) + (lane << 4));
}

// ---------------------------------------------------------------------------
// fp32 -> bf16 flat convert (n4 = n/4)
// ---------------------------------------------------------------------------
__global__ __launch_bounds__(256) void cvt_kernel(const float* __restrict__ s,
                                                  __bf16* __restrict__ d, int n4) {
  int i = blockIdx.x * 256 + threadIdx.x;
  if (i < n4) {
    float4 v = ((const float4*)s)[i];
    union { __bf16 h[4]; uint2 u; } o;
    o.h[0] = (__bf16)v.x; o.h[1] = (__bf16)v.y;
    o.h[2] = (__bf16)v.z; o.h[3] = (__bf16)v.w;
    ((uint2*)d)[i] = o.u;
  }
}

// ---------------------------------------------------------------------------
// Wt[d][hz] = (bf16)W[hz][d]   (1024x1024 transpose, 64x64 tiles)
// ---------------------------------------------------------------------------
__global__ __launch_bounds__(256) void wt_kernel(const float* __restrict__ Wk,
                                                 const float* __restrict__ Wq,
                                                 __bf16* __restrict__ Wkt,
                                                 __bf16* __restrict__ Wqt) {
  const float* W = blockIdx.z ? Wq : Wk;
  __bf16* Wt = blockIdx.z ? Wqt : Wkt;
  __shared__ __bf16 tile[64][65];
  const int r0 = blockIdx.y * 64, c0 = blockIdx.x * 64;
  const int c = threadIdx.x & 63, rb = threadIdx.x >> 6;
#pragma unroll
  for (int i = 0; i < 16; ++i) {
    int r = rb + i * 4;
    tile[r][c] = (__bf16)W[(size_t)(r0 + r) * D + c0 + c];
  }
  __syncthreads();
#pragma unroll
  for (int i = 0; i < 16; ++i) {
    int r = rb + i * 4;
    Wt[(size_t)(c0 + r) * HZ + r0 + c] = tile[c][r];
  }
}

// ---------------------------------------------------------------------------
// proj: kp/qp[bh][l][z] = sum_d x[b,l,d]*W[h,z,d]; also writes kpt/qpt[bh][z][l]
// grid (16 h, 64 m-tiles, 2 {k,q})
// ---------------------------------------------------------------------------
__global__ __launch_bounds__(256) void proj_kernel(
    const __bf16* __restrict__ xb, const __bf16* __restrict__ Wkb,
    const __bf16* __restrict__ Wqb,
    __bf16* __restrict__ kp, __bf16* __restrict__ qp,
    __bf16* __restrict__ kpt, __bf16* __restrict__ qpt) {
  const __bf16* __restrict__ Wb = blockIdx.z ? Wqb : Wkb;
  __bf16* __restrict__ outn = blockIdx.z ? qp : kp;
  __bf16* __restrict__ outt = blockIdx.z ? qpt : kpt;
  const int h = blockIdx.x, m0 = blockIdx.y * 64;
  const int tid = threadIdx.x, lane = tid & 63, w = tid >> 6;
  const int tx = lane & 15, quad = lane >> 4;
  __shared__ __align__(16) char sA[8192], sB[8192];
  const f32x4 z4 = {0.f, 0.f, 0.f, 0.f};
  f32x4 acc[4];
#pragma unroll
  for (int nb = 0; nb < 4; ++nb) acc[nb] = z4;
  for (int k0 = 0; k0 < D; k0 += 64) {
    __syncthreads();
    stage64(xb + (size_t)m0 * D + k0, D, sA, tid);
    stage64(Wb + (size_t)h * 64 * D + k0, D, sB, tid);
    __syncthreads();
#pragma unroll
    for (int t = 0; t < 2; ++t) {
      bf16x8 a = frag(sA, w, t, lane);
#pragma unroll
      for (int nb = 0; nb < 4; ++nb)
        acc[nb] = __builtin_amdgcn_mfma_f32_16x16x32_bf16(
            a, frag(sB, nb, t, lane), acc[nb], 0, 0, 0);
    }
  }
  const size_t bh = (size_t)(m0 >> 11) * H + h;
  const int l0 = (m0 & (L - 1)) + 16 * w + 4 * quad;
#pragma unroll
  for (int nb = 0; nb < 4; ++nb) {
    const int z = nb * 16 + tx;
    union { __bf16 hh[4]; uint2 u; } pk;
#pragma unroll
    for (int r = 0; r < 4; ++r) pk.hh[r] = (__bf16)acc[nb][r];
    *(uint2*)(outt + (bh * Z + z) * L + l0) = pk.u;
#pragma unroll
    for (int r = 0; r < 4; ++r) outn[(bh * L + l0 + r) * Z + z] = pk.hh[r];
  }
}

// ---------------------------------------------------------------------------
// grad0: flash forward. Gkp[q][z] = -(1/l_q) sum_k exp(b*S - m_q) qp[k][z],
// lse[q] = m_q + log l_q.  grid (32 q-tiles, 32 bh)
// ---------------------------------------------------------------------------
__global__ __launch_bounds__(256) void grad0_kernel(
    const __bf16* __restrict__ kp, const __bf16* __restrict__ qp,
    const __bf16* __restrict__ qpt, const float* __restrict__ beta_p,
    __bf16* __restrict__ Gkp, float* __restrict__ lse) {
  const int qt = blockIdx.x, bh = blockIdx.y;
  const float beta = beta_p[0];
  const int tid = threadIdx.x, lane = tid & 63, w = tid >> 6;
  const int tx = lane & 15, quad = lane >> 4;
  __shared__ __align__(16) char sR[8192], sS[8192], sT[8192];
  __shared__ __align__(16) __bf16 Ps[64][72];
  stage64(kp + ((size_t)bh * L + qt * 64) * Z, Z, sR, tid);
  const f32x4 z4 = {0.f, 0.f, 0.f, 0.f};
  f32x4 acc[4];
#pragma unroll
  for (int nb = 0; nb < 4; ++nb) acc[nb] = z4;
  float mi[4], li[4];
#pragma unroll
  for (int r = 0; r < 4; ++r) { mi[r] = -1e30f; li[r] = 0.f; }
  for (int kt = 0; kt < 32; ++kt) {
    __syncthreads();
    stage64(qp + ((size_t)bh * L + kt * 64) * Z, Z, sS, tid);
    stage64(qpt + (size_t)bh * Z * L + kt * 64, L, sT, tid);
    __syncthreads();
    f32x4 s[4];
#pragma unroll
    for (int nb = 0; nb < 4; ++nb) s[nb] = z4;
#pragma unroll
    for (int t = 0; t < 2; ++t) {
      bf16x8 a = frag(sR, w, t, lane);
#pragma unroll
      for (int nb = 0; nb < 4; ++nb)
        s[nb] = __builtin_amdgcn_mfma_f32_16x16x32_bf16(
            a, frag(sS, nb, t, lane), s[nb], 0, 0, 0);
    }
    float p[4][4];
#pragma unroll
    for (int r = 0; r < 4; ++r) {
      float v0 = s[0][r] * beta, v1 = s[1][r] * beta;
      float v2 = s[2][r] * beta, v3 = s[3][r] * beta;
      float rmax = fmaxf(fmaxf(v0, v1), fmaxf(v2, v3));
      rmax = fmaxf(rmax, __shfl_xor(rmax, 1));
      rmax = fmaxf(rmax, __shfl_xor(rmax, 2));
      rmax = fmaxf(rmax, __shfl_xor(rmax, 4));
      rmax = fmaxf(rmax, __shfl_xor(rmax, 8));
      const float mnew = fmaxf(mi[r], rmax);
      const float al = __expf(mi[r] - mnew);
      mi[r] = mnew;
      p[0][r] = __expf(v0 - mnew); p[1][r] = __expf(v1 - mnew);
      p[2][r] = __expf(v2 - mnew); p[3][r] = __expf(v3 - mnew);
      float rs = p[0][r] + p[1][r] + p[2][r] + p[3][r];
      rs += __shfl_xor(rs, 1);
      rs += __shfl_xor(rs, 2);
      rs += __shfl_xor(rs, 4);
      rs += __shfl_xor(rs, 8);
      li[r] = li[r] * al + rs;
#pragma unroll
      for (int nb = 0; nb < 4; ++nb) acc[nb][r] *= al;
    }
#pragma unroll
    for (int nb = 0; nb < 4; ++nb)
#pragma unroll
      for (int r = 0; r < 4; ++r)
        Ps[16 * w + 4 * quad + r][nb * 16 + tx] = (__bf16)p[nb][r];
    __syncthreads();
#pragma unroll
    for (int t = 0; t < 2; ++t) {
      bf16x8 pa = *(const bf16x8*)&Ps[16 * w + tx][t * 32 + quad * 8];
#pragma unroll
      for (int nb = 0; nb < 4; ++nb)
        acc[nb] = __builtin_amdgcn_mfma_f32_16x16x32_bf16(
            pa, frag(sT, nb, t, lane), acc[nb], 0, 0, 0);
    }
  }
  const int b = bh >> 4, h = bh & (H - 1);
#pragma unroll
  for (int nb = 0; nb < 4; ++nb) {
    const int z = nb * 16 + tx;
#pragma unroll
    for (int r = 0; r < 4; ++r) {
      const int q = qt * 64 + 16 * w + 4 * quad + r;
      Gkp[((size_t)b * L + q) * HZ + h * Z + z] = (__bf16)(-acc[nb][r] / li[r]);
    }
  }
  if (tx == 0) {
#pragma unroll
    for (int r = 0; r < 4; ++r)
      lse[(size_t)bh * L + qt * 64 + 16 * w + 4 * quad + r] = mi[r] + __logf(li[r]);
  }
}

// ---------------------------------------------------------------------------
// grad1: Gqp[kq][z] = -sum_q exp(b*S'[kq][q] - lse[q]) kp[q][z]
// grid (32 kq-tiles, 32 bh)
// ---------------------------------------------------------------------------
__global__ __launch_bounds__(256) void grad1_kernel(
    const __bf16* __restrict__ qp, const __bf16* __restrict__ kp,
    const __bf16* __restrict__ kpt, const float* __restrict__ beta_p,
    const float* __restrict__ lse, __bf16* __restrict__ Gqp) {
  const int rt = blockIdx.x, bh = blockIdx.y;
  const float beta = beta_p[0];
  const int tid = threadIdx.x, lane = tid & 63, w = tid >> 6;
  const int tx = lane & 15, quad = lane >> 4;
  __shared__ __align__(16) char sR[8192], sS[8192], sT[8192];
  __shared__ __align__(16) __bf16 Ps[64][72];
  stage64(qp + ((size_t)bh * L + rt * 64) * Z, Z, sR, tid);
  const f32x4 z4 = {0.f, 0.f, 0.f, 0.f};
  f32x4 acc[4];
#pragma unroll
  for (int nb = 0; nb < 4; ++nb) acc[nb] = z4;
  for (int kt = 0; kt < 32; ++kt) {
    __syncthreads();
    stage64(kp + ((size_t)bh * L + kt * 64) * Z, Z, sS, tid);
    stage64(kpt + (size_t)bh * Z * L + kt * 64, L, sT, tid);
    float lsec[4];
#pragma unroll
    for (int nb = 0; nb < 4; ++nb)
      lsec[nb] = lse[(size_t)bh * L + kt * 64 + nb * 16 + tx];
    __syncthreads();
    f32x4 s[4];
#pragma unroll
    for (int nb = 0; nb < 4; ++nb) s[nb] = z4;
#pragma unroll
    for (int t = 0; t < 2; ++t) {
      bf16x8 a = frag(sR, w, t, lane);
#pragma unroll
      for (int nb = 0; nb < 4; ++nb)
        s[nb] = __builtin_amdgcn_mfma_f32_16x16x32_bf16(
            a, frag(sS, nb, t, lane), s[nb], 0, 0, 0);
    }
#pragma unroll
    for (int nb = 0; nb < 4; ++nb)
#pragma unroll
      for (int r = 0; r < 4; ++r)
        Ps[16 * w + 4 * quad + r][nb * 16 + tx] =
            (__bf16)__expf(s[nb][r] * beta - lsec[nb]);
    __syncthreads();
#pragma unroll
    for (int t = 0; t < 2; ++t) {
      bf16x8 pa = *(const bf16x8*)&Ps[16 * w + tx][t * 32 + quad * 8];
#pragma unroll
      for (int nb = 0; nb < 4; ++nb)
        acc[nb] = __builtin_amdgcn_mfma_f32_16x16x32_bf16(
            pa, frag(sT, nb, t, lane), acc[nb], 0, 0, 0);
    }
  }
  const int b = bh >> 4, h = bh & (H - 1);
#pragma unroll
  for (int nb = 0; nb < 4; ++nb) {
    const int z = nb * 16 + tx;
#pragma unroll
    for (int r = 0; r < 4; ++r) {
      const int kq = rt * 64 + 16 * w + 4 * quad + r;
      Gqp[((size_t)b * L + kq) * HZ + h * Z + z] = (__bf16)(-acc[nb][r]);
    }
  }
}

// ---------------------------------------------------------------------------
// en[b] = -(1/beta) * sum_{h,q} lse[b,h,q]
// ---------------------------------------------------------------------------
__global__ __launch_bounds__(256) void energy_kernel(
    const float* __restrict__ lse_ws, const float* __restrict__ beta_p,
    float* __restrict__ out) {
  const int b = blockIdx.x;
  const float* p = lse_ws + (size_t)b * H * L;
  float sum = 0.f;
  for (int i = threadIdx.x; i < H * L; i += 256) sum += p[i];
#pragma unroll
  for (int off = 1; off < 64; off <<= 1) sum += __shfl_xor(sum, off, 64);
  __shared__ float wsum[4];
  if ((threadIdx.x & 63) == 0) wsum[threadIdx.x >> 6] = sum;
  __syncthreads();
  if (threadIdx.x == 0)
    out[b] = -(wsum[0] + wsum[1] + wsum[2] + wsum[3]) / beta_p[0];
}

// ---------------------------------------------------------------------------
// gx[m][d] = sum_hz Gkp[m][hz]*Wk[hz][d] + Gqp[m][hz]*Wq[hz][d]
// grid (16 d-tiles, 64 m-tiles)
// ---------------------------------------------------------------------------
__global__ __launch_bounds__(256) void gx_kernel(
    const __bf16* __restrict__ Gkp, const __bf16* __restrict__ Gqp,
    const __bf16* __restrict__ Wkt, const __bf16* __restrict__ Wqt,
    float* __restrict__ gx) {
  const int n0 = blockIdx.x * 64, m0 = blockIdx.y * 64;
  const int tid = threadIdx.x, lane = tid & 63, w = tid >> 6;
  const int tx = lane & 15, quad = lane >> 4;
  __shared__ __align__(16) char sA[8192], sB[8192];
  const f32x4 z4 = {0.f, 0.f, 0.f, 0.f};
  f32x4 acc[4];
#pragma unroll
  for (int nb = 0; nb < 4; ++nb) acc[nb] = z4;
#pragma unroll 1
  for (int src = 0; src < 2; ++src) {
    const __bf16* __restrict__ A = src ? Gqp : Gkp;
    const __bf16* __restrict__ Bt = src ? Wqt : Wkt;
    for (int k0 = 0; k0 < HZ; k0 += 64) {
      __syncthreads();
      stage64(A + (size_t)m0 * HZ + k0, HZ, sA, tid);
      stage64(Bt + (size_t)n0 * HZ + k0, HZ, sB, tid);
      __syncthreads();
#pragma unroll
      for (int t = 0; t < 2; ++t) {
        bf16x8 a = frag(sA, w, t, lane);
#pragma unroll
        for (int nb = 0; nb < 4; ++nb)
          acc[nb] = __builtin_amdgcn_mfma_f32_16x16x32_bf16(
              a, frag(sB, nb, t, lane), acc[nb], 0, 0, 0);
      }
    }
  }
#pragma unroll
  for (int nb = 0; nb < 4; ++nb)
#pragma unroll
    for (int r = 0; r < 4; ++r)
      gx[(size_t)(m0 + 16 * w + 4 * quad + r) * D + n0 + nb * 16 + tx] =
          acc[nb][r];
}

// ---------------------------------------------------------------------------
extern "C" void kernel_launch(void* const* d_in, const int* in_sizes, int n_in,
                              void* d_out, int out_size, void* d_ws, size_t ws_size,
                              hipStream_t stream) {
  const float* x    = (const float*)d_in[0];
  const float* Wq   = (const float*)d_in[1];
  const float* Wk   = (const float*)d_in[2];
  const float* beta = (const float*)d_in[3];
  float* out = (float*)d_out;

  // workspace layout (bytes):
  char* ws = (char*)d_ws;
  __bf16* xb  = (__bf16*)(ws);                         // 8 MB
  __bf16* Wkb = (__bf16*)(ws + (8ull  << 20));         // 2 MB
  __bf16* Wqb = (__bf16*)(ws + (10ull << 20));         // 2 MB
  __bf16* Wkt = (__bf16*)(ws + (12ull << 20));         // 2 MB
  __bf16* Wqt = (__bf16*)(ws + (14ull << 20));         // 2 MB
  __bf16* kp  = (__bf16*)(ws + (16ull << 20));         // 8 MB
  __bf16* qp  = (__bf16*)(ws + (24ull << 20));         // 8 MB
  __bf16* kpt = (__bf16*)(ws + (32ull << 20));         // 8 MB
  __bf16* qpt = (__bf16*)(ws + (40ull << 20));         // 8 MB
  __bf16* Gkp = (__bf16*)(ws + (48ull << 20));         // 8 MB
  __bf16* Gqp = (__bf16*)(ws + (56ull << 20));         // 8 MB
  float*  lse = (float*)(ws + (64ull << 20));          // 256 KB

  cvt_kernel<<<4096, 256, 0, stream>>>(x, xb, 1048576);
  cvt_kernel<<<1024, 256, 0, stream>>>(Wk, Wkb, 262144);
  cvt_kernel<<<1024, 256, 0, stream>>>(Wq, Wqb, 262144);
  wt_kernel<<<dim3(16, 16, 2), 256, 0, stream>>>(Wk, Wq, Wkt, Wqt);
  proj_kernel<<<dim3(16, 64, 2), 256, 0, stream>>>(xb, Wkb, Wqb, kp, qp, kpt, qpt);
  grad0_kernel<<<dim3(32, 32), 256, 0, stream>>>(kp, qp, qpt, beta, Gkp, lse);
  grad1_kernel<<<dim3(32, 32), 256, 0, stream>>>(qp, kp, kpt, beta, lse, Gqp);
  energy_kernel<<<2, 256, 0, stream>>>(lse, beta, out);
  gx_kernel<<<dim3(16, 64), 256, 0, stream>>>(Gkp, Gqp, Wkt, Wqt, out + 2);
}